// Round 5
// baseline (1461.993 us; speedup 1.0000x reference)
//
#include <hip/hip_runtime.h>
#include <stdint.h>

#define NPTS   8192
#define NB     4
#define KNN    20
#define NROWS  (NB * NPTS)        // 32768
#define MTOTF  655360.0f          // NROWS * KNN
#define WPB    8                  // waves (= rows) per block
#define BLK    (WPB * 64)         // 512 threads
#define QSTEPS 32                 // 32 steps x 64 lanes x 4 cand = 8192
#define BUFCAP 192                // survivor buffer per row (expect ~24)
#define ACCN   32                 // spread accumulator slots (pairs)
#define FINF   3.0e38f

__device__ __forceinline__ int mbcnt64(unsigned long long m) {
    return __builtin_amdgcn_mbcnt_hi((unsigned)(m >> 32),
           __builtin_amdgcn_mbcnt_lo((unsigned)m, 0));
}

__device__ __forceinline__ float wave_min_f(float v) {
#pragma unroll
    for (int m = 1; m < 64; m <<= 1) v = fminf(v, __shfl_xor(v, m, 64));
    return v;
}

// One row per wave. Pass A: per-lane min of 128 candidates -> tau = 20th
// smallest of the 64 lane-minima (a 64-element subset of the row's d2 set,
// so its 20th-smallest >= the true 20th: safe gate, expected rank ~24).
// Pass B: rescan, compact all d2 <= tau to LDS (all true top-20 included).
// Pass C: exact 20-extraction over survivors -> kmin/kmax/sum/sum2.
__global__ __launch_bounds__(BLK, 8) void knn_kernel(
    const float* __restrict__ x,
    float* __restrict__ kmaxA, float* __restrict__ kminA, float* __restrict__ acc)
{
    __shared__ float buf[WPB][BUFCAP];   // 6 KB
    __shared__ float ssum[WPB * 2];

    const int tid  = threadIdx.x;
    const int lane = tid & 63;
    const int wave = tid >> 6;
    const int row  = blockIdx.x * WPB + wave;
    const int b    = row >> 13;               // 1024 blocks per batch, aligned
    const int n    = row & (NPTS - 1);
    const float* xb = x + b * 3 * NPTS;

    const float px = xb[n];
    const float py = xb[NPTS + n];
    const float pz = xb[2 * NPTS + n];

    // ---- Pass A: per-lane min over 128 candidates (quad loads) ----
    float m1 = FINF;
    for (int s = 0; s < QSTEPS; ++s) {
        const int m = s * 256 + lane * 4;
        const float4 qx = *(const float4*)(xb + m);
        const float4 qy = *(const float4*)(xb + NPTS + m);
        const float4 qz = *(const float4*)(xb + 2 * NPTS + m);
        float ax, ay, az;
        ax = qx.x - px; ay = qy.x - py; az = qz.x - pz;
        const float d0 = fmaf(ax, ax, fmaf(ay, ay, az * az));
        ax = qx.y - px; ay = qy.y - py; az = qz.y - pz;
        const float d1 = fmaf(ax, ax, fmaf(ay, ay, az * az));
        ax = qx.z - px; ay = qy.z - py; az = qz.z - pz;
        const float d2 = fmaf(ax, ax, fmaf(ay, ay, az * az));
        ax = qx.w - px; ay = qy.w - py; az = qz.w - pz;
        const float d3 = fmaf(ax, ax, fmaf(ay, ay, az * az));
        m1 = fminf(m1, fminf(fminf(d0, d1), fminf(d2, d3)));
    }

    // tau = 20th smallest of the 64 lane minima (extraction by wave-min)
    float v = m1, tau = FINF;
#pragma unroll 1
    for (int k = 0; k < KNN; ++k) {
        const float g = wave_min_f(v);
        const unsigned long long msk = __ballot(v == g);
        if (lane == (int)__builtin_ctzll(msk)) v = FINF;
        tau = g;
    }

    // ---- Pass B: compact all d2 <= tau (L1-warm rescan) ----
    float* mybuf = buf[wave];
    int cnt = 0;                               // wave-uniform
    for (int s = 0; s < QSTEPS; ++s) {
        const int m = s * 256 + lane * 4;
        const float4 qx = *(const float4*)(xb + m);
        const float4 qy = *(const float4*)(xb + NPTS + m);
        const float4 qz = *(const float4*)(xb + 2 * NPTS + m);
        float ax, ay, az;
        ax = qx.x - px; ay = qy.x - py; az = qz.x - pz;
        const float d0 = fmaf(ax, ax, fmaf(ay, ay, az * az));
        ax = qx.y - px; ay = qy.y - py; az = qz.y - pz;
        const float d1 = fmaf(ax, ax, fmaf(ay, ay, az * az));
        ax = qx.z - px; ay = qy.z - py; az = qz.z - pz;
        const float d2 = fmaf(ax, ax, fmaf(ay, ay, az * az));
        ax = qx.w - px; ay = qy.w - py; az = qz.w - pz;
        const float d3 = fmaf(ax, ax, fmaf(ay, ay, az * az));
        const bool k0 = d0 <= tau, k1 = d1 <= tau, k2 = d2 <= tau, k3 = d3 <= tau;
        if (__ballot(k0 || k1 || k2 || k3)) {
            unsigned long long bm;
            int o;
            bm = __ballot(k0); o = cnt + mbcnt64(bm);
            if (k0 && o < BUFCAP) mybuf[o] = d0;
            cnt += (int)__popcll(bm);
            bm = __ballot(k1); o = cnt + mbcnt64(bm);
            if (k1 && o < BUFCAP) mybuf[o] = d1;
            cnt += (int)__popcll(bm);
            bm = __ballot(k2); o = cnt + mbcnt64(bm);
            if (k2 && o < BUFCAP) mybuf[o] = d2;
            cnt += (int)__popcll(bm);
            bm = __ballot(k3); o = cnt + mbcnt64(bm);
            if (k3 && o < BUFCAP) mybuf[o] = d3;
            cnt += (int)__popcll(bm);
        }
    }
    const int c = cnt < BUFCAP ? cnt : BUFCAP;

    // ---- Pass C: exact top-20 extraction over survivors (<=192, 3/lane) ----
    float s0 = (lane < c)       ? mybuf[lane]       : FINF;
    float s1 = (lane + 64 < c)  ? mybuf[lane + 64]  : FINF;
    float s2 = (lane + 128 < c) ? mybuf[lane + 128] : FINF;
    // sort3 ascending
    { float lo = fminf(s0, s1), hi = fmaxf(s0, s1); s0 = lo; s1 = hi; }
    { float lo = fminf(s1, s2), hi = fmaxf(s1, s2); s1 = lo; s2 = hi; }
    { float lo = fminf(s0, s1), hi = fmaxf(s0, s1); s0 = lo; s1 = hi; }

    float sum = 0.f, sum2 = 0.f, dmin = 0.f, dmax = 0.f;
#pragma unroll 1
    for (int k = 0; k < KNN; ++k) {
        const float g = wave_min_f(s0);
        const unsigned long long msk = __ballot(s0 == g);
        if (lane == (int)__builtin_ctzll(msk)) { s0 = s1; s1 = s2; s2 = FINF; }
        const float gd = fmaxf(g, 0.f);
        const float d = sqrtf(gd);
        sum += d; sum2 += gd;
        if (k == 0) dmin = d;
        dmax = d;                             // k = 19 -> 20th smallest
    }

    if (lane == 0) {
        kmaxA[row] = dmax;
        kminA[row] = dmin;
        ssum[wave * 2]     = sum;
        ssum[wave * 2 + 1] = sum2;
    }
    __syncthreads();
    if (tid == 0) {
        float S = 0.f, S2 = 0.f;
#pragma unroll
        for (int r = 0; r < WPB; ++r) { S += ssum[r * 2]; S2 += ssum[r * 2 + 1]; }
        const int slot = (int)(blockIdx.x & (ACCN - 1));
        atomicAdd(acc + slot * 2,     S);
        atomicAdd(acc + slot * 2 + 1, S2);
    }
}

// out[b,c,n] = lrelu(a_c * (a_c>=0 ? kmax : kmin) + d_c); BN coefs inline
// (conv bias cancels inside BN: feat - mean_c = w_c*(knn - mu)).
__global__ __launch_bounds__(256) void out_kernel(
    const float* __restrict__ kmaxA, const float* __restrict__ kminA,
    const float* __restrict__ acc,
    const float* __restrict__ w, const float* __restrict__ gamma,
    const float* __restrict__ beta, float* __restrict__ out)
{
    const int r = blockIdx.x * 256 + threadIdx.x;   // 0..32767
    const int b = r >> 13;
    const int n = r & (NPTS - 1);
    float S = 0.f, S2 = 0.f;
#pragma unroll
    for (int i = 0; i < ACCN; ++i) { S += acc[2 * i]; S2 += acc[2 * i + 1]; }
    const float mu = S * (1.0f / MTOTF);
    float var = S2 * (1.0f / MTOTF) - mu * mu;
    var = fmaxf(var, 0.f);
    const float kmax = kmaxA[r];
    const float kmin = kminA[r];
#pragma unroll
    for (int c = 0; c < 16; ++c) {
        const float wc = w[c];
        const float a = gamma[c] * wc * rsqrtf(wc * wc * var + 1e-5f);
        const float d = beta[c] - a * mu;
        float v = a * (a >= 0.f ? kmax : kmin) + d;
        v = (v >= 0.f) ? v : 0.2f * v;
        out[(b * 16 + c) * NPTS + n] = v;
    }
}

extern "C" void kernel_launch(void* const* d_in, const int* in_sizes, int n_in,
                              void* d_out, int out_size, void* d_ws, size_t ws_size,
                              hipStream_t stream)
{
    const float* x     = (const float*)d_in[0];
    const float* w     = (const float*)d_in[1];
    const float* gamma = (const float*)d_in[3];
    const float* beta  = (const float*)d_in[4];
    float* out = (float*)d_out;
    float* ws  = (float*)d_ws;

    float* kmaxA = ws;                       // NROWS floats
    float* kminA = ws + NROWS;               // NROWS floats
    float* acc   = ws + 2 * NROWS;           // ACCN*2 floats

    hipMemsetAsync(acc, 0, ACCN * 2 * sizeof(float), stream);
    knn_kernel<<<NROWS / WPB, BLK, 0, stream>>>(x, kmaxA, kminA, acc);
    out_kernel<<<NROWS / 256, 256, 0, stream>>>(kmaxA, kminA, acc, w, gamma, beta, out);
}

// Round 8
// 320.840 us; speedup vs baseline: 4.5568x; 4.5568x over previous
//
#include <hip/hip_runtime.h>
#include <stdint.h>

#define NPTS  8192
#define NB    4
#define KNN   20
#define NROWS (NB * NPTS)        // 32768
#define MTOTF 655360.0f          // NROWS * KNN
#define WPB   8                  // waves per block; all share the same 64 rows
#define BLK   (WPB * 64)         // 512 threads
#define SLICE (NPTS / WPB)       // 1024 candidates per wave
#define PAIRS (SLICE / 2)        // 512 pairs per wave
#define LSTR  (KNN + 1)          // padded LDS list stride (21, odd -> conflict-free)
#define ACCN  32                 // spread accumulator slots (pairs)

typedef _Float16 f16x2 __attribute__((ext_vector_type(2)));

__device__ __forceinline__ f16x2 pmin2(f16x2 a, f16x2 b) {
    return __builtin_elementwise_min(a, b);    // v_pk_min_f16
}
__device__ __forceinline__ f16x2 pmax2(f16x2 a, f16x2 b) {
    return __builtin_elementwise_max(a, b);    // v_pk_max_f16
}
__device__ __forceinline__ f16x2 pkrtz2(float a, float b) {
    return __builtin_bit_cast(f16x2, __builtin_amdgcn_cvt_pkrtz(a, b));
}

// Prep: tile4[b*NPTS+m] = (qx,qy,qz,0) AoS for scalar-pipe streaming; zero acc.
__global__ __launch_bounds__(256) void prep_kernel(
    const float* __restrict__ x, float4* __restrict__ tile4, float* __restrict__ acc)
{
    const int i = blockIdx.x * 256 + threadIdx.x;    // 0..32767
    const int b = i >> 13;
    const int m = i & (NPTS - 1);
    const float* xb = x + b * 3 * NPTS;
    tile4[i] = make_float4(xb[m], xb[NPTS + m], xb[2 * NPTS + m], 0.f);
    if (i < ACCN * 2) acc[i] = 0.f;
}

// K1: lane = row (64 rows/block); 8 waves each scan a 1024-candidate slice via
// wave-uniform (scalar-pipe) loads. Each lane keeps TWO interleaved ascending
// top-20 lists of f16 d2 in the halves of 20 VGPRs; insert = v_pk_max(v_pk_min)
// chain (full-rate, 2 candidates per 20-op pass). Cross-wave merge via LDS.
__global__ __launch_bounds__(BLK) void knn_kernel(
    const float* __restrict__ x, const float4* __restrict__ tile4,
    float* __restrict__ kmaxA, float* __restrict__ kminA, float* __restrict__ acc)
{
    __shared__ uint32_t lists[(WPB - 1) * 64 * LSTR];   // 37632 B

    const int tid  = threadIdx.x;
    const int lane = tid & 63;
    const int wave = __builtin_amdgcn_readfirstlane(tid >> 6);
    const int rowBase = blockIdx.x * 64;
    const int row  = rowBase + lane;
    const int b    = rowBase >> 13;          // 128 blocks per batch
    const int n    = row & (NPTS - 1);
    const float* xb = x + b * 3 * NPTS;

    const float px = xb[n];
    const float py = xb[NPTS + n];
    const float pz = xb[2 * NPTS + n];

    const f16x2 INF2 = __builtin_bit_cast(f16x2, 0x7C007C00u);   // (+inf, +inf)
    f16x2 arr[KNN];                          // two ascending d2 lists (lo/hi halves)
#pragma unroll
    for (int j = 0; j < KNN; ++j) arr[j] = INF2;

    const float4* __restrict__ tp = tile4 + b * NPTS + wave * SLICE;
#pragma unroll 4
    for (int i = 0; i < PAIRS; ++i) {
        const float4 q0 = tp[2 * i];         // wave-uniform -> scalar loads
        const float4 q1 = tp[2 * i + 1];
        float dx = q0.x - px, dy = q0.y - py, dz = q0.z - pz;
        const float d2a = fmaf(dx, dx, fmaf(dy, dy, dz * dz));
        dx = q1.x - px; dy = q1.y - py; dz = q1.z - pz;
        const float d2b = fmaf(dx, dx, fmaf(dy, dy, dz * dz));
        const f16x2 dp = pkrtz2(d2a, d2b);
        // branchless sorted insert (ascending, drop largest) in both halves:
        // med3(d, lo, hi) == max(lo, min(d, hi)) for lo<=hi
#pragma unroll
        for (int j = KNN - 1; j > 0; --j)
            arr[j] = pmax2(arr[j - 1], pmin2(dp, arr[j]));
        arr[0] = pmin2(arr[0], dp);
    }

    // waves 1..7 dump pair-lists; wave 0 absorbs 7*20 pairs per lane
    if (wave > 0) {
        uint32_t* dst = lists + ((wave - 1) * 64 + lane) * LSTR;
#pragma unroll
        for (int j = 0; j < KNN; ++j) dst[j] = __builtin_bit_cast(uint32_t, arr[j]);
    }
    __syncthreads();

    if (wave == 0) {
        for (int wsrc = 0; wsrc < WPB - 1; ++wsrc) {
            const uint32_t* src = lists + (wsrc * 64 + lane) * LSTR;
#pragma unroll
            for (int k = 0; k < KNN; ++k) {
                const f16x2 v = __builtin_bit_cast(f16x2, src[k]);
#pragma unroll
                for (int j = KNN - 1; j > 0; --j)
                    arr[j] = pmax2(arr[j - 1], pmin2(v, arr[j]));
                arr[0] = pmin2(arr[0], v);
            }
        }
        // Batcher lower-halver: the 20 smallest of two ascending 20-lists A,B
        // form { min(A[j], B[19-j]) }, static indices only.
        float sum = 0.f, sum2 = 0.f, dmn = 3.0e38f, dmx = 0.f;
#pragma unroll
        for (int j = 0; j < KNN; ++j) {
            const float A  = (float)arr[j][0];
            const float Bv = (float)arr[KNN - 1 - j][1];
            const float d2 = fmaxf(fminf(A, Bv), 0.f);
            const float d  = sqrtf(d2);
            sum += d; sum2 += d2;
            dmn = fminf(dmn, d);
            dmx = fmaxf(dmx, d);
        }
        kmaxA[row] = dmx;
        kminA[row] = dmn;
#pragma unroll
        for (int o = 32; o; o >>= 1) {
            sum  += __shfl_down(sum,  o, 64);
            sum2 += __shfl_down(sum2, o, 64);
        }
        if (lane == 0) {
            const int slot = (int)(blockIdx.x & (ACCN - 1));
            atomicAdd(acc + slot * 2,     sum);
            atomicAdd(acc + slot * 2 + 1, sum2);
        }
    }
}

// K2: out[b,c,n] = lrelu(a_c * (a_c>=0 ? kmax : kmin) + d_c); BN coefs inline
// (conv bias cancels inside BN: feat - mean_c = w_c*(knn - mu)).
__global__ __launch_bounds__(256) void out_kernel(
    const float* __restrict__ kmaxA, const float* __restrict__ kminA,
    const float* __restrict__ acc,
    const float* __restrict__ w, const float* __restrict__ gamma,
    const float* __restrict__ beta, float* __restrict__ out)
{
    const int r = blockIdx.x * 256 + threadIdx.x;   // 0..32767
    const int b = r >> 13;
    const int n = r & (NPTS - 1);
    float S = 0.f, S2 = 0.f;
#pragma unroll
    for (int i = 0; i < ACCN; ++i) { S += acc[2 * i]; S2 += acc[2 * i + 1]; }
    const float mu = S * (1.0f / MTOTF);
    float var = S2 * (1.0f / MTOTF) - mu * mu;
    var = fmaxf(var, 0.f);
    const float kmax = kmaxA[r];
    const float kmin = kminA[r];
#pragma unroll
    for (int c = 0; c < 16; ++c) {
        const float wc = w[c];
        const float a = gamma[c] * wc * rsqrtf(wc * wc * var + 1e-5f);
        const float d = beta[c] - a * mu;
        float v = a * (a >= 0.f ? kmax : kmin) + d;
        v = (v >= 0.f) ? v : 0.2f * v;
        out[(b * 16 + c) * NPTS + n] = v;
    }
}

extern "C" void kernel_launch(void* const* d_in, const int* in_sizes, int n_in,
                              void* d_out, int out_size, void* d_ws, size_t ws_size,
                              hipStream_t stream)
{
    const float* x     = (const float*)d_in[0];
    const float* w     = (const float*)d_in[1];
    const float* gamma = (const float*)d_in[3];
    const float* beta  = (const float*)d_in[4];
    float* out = (float*)d_out;
    float* ws  = (float*)d_ws;

    float* kmaxA = ws;                        // NROWS floats
    float* kminA = ws + NROWS;                // NROWS floats
    float* acc   = ws + 2 * NROWS;            // ACCN*2 floats
    float4* tile4 = (float4*)(ws + 2 * NROWS + ACCN * 2);   // 16B-aligned offset

    prep_kernel<<<NROWS / 256, 256, 0, stream>>>(x, tile4, acc);
    knn_kernel<<<NROWS / 64, BLK, 0, stream>>>(x, tile4, kmaxA, kminA, acc);
    out_kernel<<<NROWS / 256, 256, 0, stream>>>(kmaxA, kminA, acc, w, gamma, beta, out);
}